// Round 12
// baseline (102.244 us; speedup 1.0000x reference)
//
#include <hip/hip_runtime.h>
#include <hip/hip_bf16.h>

#define B_ 8
#define D_ 128
#define NH 8
#define L_ 1024
#define DK 16

typedef __attribute__((ext_vector_type(4))) short s4;
typedef __attribute__((ext_vector_type(4))) float f4;

static __device__ __forceinline__ unsigned short f2bf(float f) {
    __hip_bfloat16 h = __float2bfloat16(f);
    return *reinterpret_cast<unsigned short*>(&h);
}
static __device__ __forceinline__ unsigned pack2(float a, float b) {
    return (unsigned)f2bf(a) | ((unsigned)f2bf(b) << 16);
}
static __device__ __forceinline__ s4 pack4(float a, float b, float c, float d) {
    union { unsigned u[2]; s4 v; } un;
    un.u[0] = pack2(a, b);
    un.u[1] = pack2(c, d);
    return un.v;
}

// exp2 via native trans op (K pre-scaled by 0.25*log2(e) so exp(S)=exp2(S')).
static __device__ __forceinline__ float fexp2(float x) {
#if __has_builtin(__builtin_amdgcn_exp2f)
    return __builtin_amdgcn_exp2f(x);
#else
    float r; asm("v_exp_f32 %0, %1" : "=v"(r) : "v"(x)); return r;
#endif
}

// 16x16x16 bf16 MFMA: D = A*B + C.  A[m=lane&15][k=(lane>>4)*4+jj],
// B[k=(lane>>4)*4+jj][n=lane&15], C/D[row=(lane>>4)*4+reg][col=lane&15].
#if __has_builtin(__builtin_amdgcn_mfma_f32_16x16x16_bf16)
#define MFMA16(a, b, c) __builtin_amdgcn_mfma_f32_16x16x16_bf16(a, b, c, 0, 0, 0)
#elif __has_builtin(__builtin_amdgcn_mfma_f32_16x16x16bf16_1k)
#define MFMA16(a, b, c) __builtin_amdgcn_mfma_f32_16x16x16bf16_1k(a, b, c, 0, 0, 0)
#else
static __device__ __forceinline__ f4 mfma16_asm(s4 a, s4 b, f4 c) {
    f4 d;
    asm volatile("v_mfma_f32_16x16x16_bf16 %0, %1, %2, %3"
                 : "=&v"(d) : "v"(a), "v"(b), "v"(c));
    return d;
}
#define MFMA16(a, b, c) mfma16_asm(a, b, c)
#endif

// ---------------------------------------------------------------------------
// Kernel 1: FUSED QKV projection (unchanged from R3 -- measured ~5us).
// grid (16, 64), block 256.
// ---------------------------------------------------------------------------
__global__ __launch_bounds__(256)
void proj_kernel(const float* __restrict__ x,
                 const float* __restrict__ Wq,
                 const float* __restrict__ Wk,
                 const float* __restrict__ Wv,
                 unsigned short* __restrict__ Qt,
                 unsigned short* __restrict__ Kt,
                 unsigned short* __restrict__ Vt) {
    const int lane = threadIdx.x & 63;
    const int wv   = threadIdx.x >> 6;
    const int m = lane & 15, q = lane >> 4;
    const int bh = blockIdx.y, b = bh >> 3, h = bh & 7;
    const int n0 = (blockIdx.x * 4 + wv) * 16;

    const size_t wrow_off = ((size_t)((h * B_ + b) * DK + m)) * D_;  // A row m
    const float* Wqr = Wq + wrow_off;
    const float* Wkr = Wk + wrow_off;
    const float* Wvr = Wv + wrow_off;
    const float* xb = x + (size_t)b * D_ * L_ + n0 + m;

    f4 aQ = {0.f, 0.f, 0.f, 0.f}, aK = {0.f, 0.f, 0.f, 0.f}, aV = {0.f, 0.f, 0.f, 0.f};
#pragma unroll
    for (int kb = 0; kb < 8; ++kb) {
        const int k4 = kb * 16 + q * 4;

        const float* xc = xb + (size_t)k4 * L_;
        float b0 = xc[0], b1 = xc[L_], b2 = xc[2 * L_], b3 = xc[3 * L_];
        s4 bf = pack4(b0, b1, b2, b3);

        float4 wq = *(const float4*)(Wqr + k4);
        float4 wk = *(const float4*)(Wkr + k4);
        float4 wv4 = *(const float4*)(Wvr + k4);
        s4 fq = pack4(wq.x, wq.y, wq.z, wq.w);
        s4 fk = pack4(wk.x, wk.y, wk.z, wk.w);
        s4 fv = pack4(wv4.x, wv4.y, wv4.z, wv4.w);

        aQ = MFMA16(fq, bf, aQ);
        aK = MFMA16(fk, bf, aK);
        aV = MFMA16(fv, bf, aV);
    }

    // Epilogues.  C layout: [row = q*4 + r][col = m] (row = dk, col = l).
    uint2 uq;
    uq.x = pack2(aQ[0], aQ[1]);
    uq.y = pack2(aQ[2], aQ[3]);
    *(uint2*)(Qt + ((size_t)bh * L_ + n0 + m) * DK + q * 4) = uq;

    const float sc = 0.25f * 1.4426950408889634f;   // 1/sqrt(Dk) * log2(e)
    uint2 uk;
    uk.x = pack2(aK[0] * sc, aK[1] * sc);
    uk.y = pack2(aK[2] * sc, aK[3] * sc);
    *(uint2*)(Kt + ((size_t)bh * L_ + n0 + m) * DK + q * 4) = uk;

    unsigned short* vp = Vt + ((size_t)bh * DK + q * 4) * L_ + n0 + m;
    vp[0]      = f2bf(aV[0]); vp[L_]     = f2bf(aV[1]);
    vp[2 * L_] = f2bf(aV[2]); vp[3 * L_] = f2bf(aV[3]);
}

// ---------------------------------------------------------------------------
// Kernel 2: attention with LDS-RESIDENT Q/V (R9 structure, measured as part
// of attn+outproj = 26us).  Block (jg, bh) stages this head's whole Q (32KB)
// + V (32KB) into LDS once in fragment order; 16 waves each own a 16-wide
// j-tile over the FULL i range.  No global loads in the hot loop.
// R10 delta: head tile now written to Ht[b][j][d] (d contiguous) as ONE
// uint2 store (was 4x 2B scalar stores at 2KB stride).
// grid (4, 64), block 1024.
// ---------------------------------------------------------------------------
__global__ __launch_bounds__(1024)
void attn_kernel(const unsigned short* __restrict__ Qt,
                 const unsigned short* __restrict__ Kt,
                 const unsigned short* __restrict__ Vt,
                 unsigned short* __restrict__ Ht) {
    const int tid  = threadIdx.x;
    const int lane = tid & 63;
    const int wid  = tid >> 6;              // 0..15
    const int m = lane & 15, q = lane >> 4;
    const int jg = blockIdx.x, bh = blockIdx.y;

    // frag[it][lane]: Qf -> Q[it*16+m][q*4+j], Vf -> V[m][it*16+q*4+j]
    __shared__ s4 Qf[64 * 64];              // 32 KB
    __shared__ s4 Vf[64 * 64];              // 32 KB

    const unsigned short* Qg = Qt + (size_t)bh * L_ * DK;
    const unsigned short* Vg = Vt + (size_t)bh * DK * L_;
#pragma unroll
    for (int c = 0; c < 4; ++c) {
        const int e  = c * 1024 + tid;
        const int it = e >> 6;
        const int em = e & 15;
        const int eq = (e >> 4) & 3;
        // Q[l = it*16+em][k = eq*4 ..+4]
        Qf[e] = *(const s4*)(Qg + (size_t)(it * 16 + em) * DK + eq * 4);
        // V[v = em][i = it*16+eq*4 ..+4]
        Vf[e] = *(const s4*)(Vg + (size_t)em * L_ + it * 16 + eq * 4);
    }

    const int j0 = jg * 256 + wid * 16;
    s4 bk = *(const s4*)(Kt + ((size_t)bh * L_ + j0 + m) * DK + q * 4);

    __syncthreads();

    f4 O = {0.f, 0.f, 0.f, 0.f};
    float ls = 0.f;
#pragma unroll 8
    for (int it = 0; it < 64; ++it) {
        s4 aq = Qf[it * 64 + lane];
        s4 av = Vf[it * 64 + lane];

        f4 z = {0.f, 0.f, 0.f, 0.f};
        f4 S = MFMA16(aq, bk, z);       // S[it*16+q*4+r][j0+m]  (*log2e)

        float p0 = fexp2(S[0]), p1 = fexp2(S[1]);
        float p2 = fexp2(S[2]), p3 = fexp2(S[3]);
        ls += (p0 + p1) + (p2 + p3);

        s4 pb;
        pb[0] = (short)f2bf(p0); pb[1] = (short)f2bf(p1);
        pb[2] = (short)f2bf(p2); pb[3] = (short)f2bf(p3);

        O = MFMA16(av, pb, O);          // O[v=q*4+r][j0+m] += V*P
    }

    // sum the 4 q-group partial column-sums (rows of S are split across q)
    ls += __shfl_xor(ls, 16, 64);
    ls += __shfl_xor(ls, 32, 64);
    const float inv = 1.f / ls;

    // Ht[b][j][d]: lane writes d = h*16 + q*4 .. +3 at j = j0+m -> one uint2.
    const int b = bh >> 3, h = bh & 7;
    uint2 ho;
    ho.x = pack2(O[0] * inv, O[1] * inv);
    ho.y = pack2(O[2] * inv, O[3] * inv);
    *(uint2*)(Ht + ((size_t)b * L_ + j0 + m) * D_ + h * 16 + q * 4) = ho;
}

// ---------------------------------------------------------------------------
// Kernel 3: output projection out[b] = Wo[b] @ Ht[b].  R10 delta: Ht is
// [b][j][d] so the B-fragment B[k=d][n=j] = Ht[b][j16+m][k4..k4+3] is ONE
// s4 (8B) load (was 4x 2B gathers at 2KB stride -- the R7/R8 serialized-
// gather pathology in miniature).  grid (32, 8), block 1024.
// ---------------------------------------------------------------------------
__global__ __launch_bounds__(1024)
void outproj_kernel(const unsigned short* __restrict__ Ht,
                    const float* __restrict__ Wo,
                    float* __restrict__ out) {
    const int lane = threadIdx.x & 63;
    const int wid  = threadIdx.x >> 6;
    const int m = lane & 15, q = lane >> 4;
    const int b = blockIdx.y;
    const int oc = wid & 7, jt = wid >> 3;
    const int j16 = blockIdx.x * 32 + jt * 16;
    const int o0 = oc * 16;

    const float* Wrow = Wo + ((size_t)b * D_ + o0 + m) * D_;   // A row m
    const unsigned short* Hrow = Ht + ((size_t)b * L_ + j16 + m) * D_;

    f4 acc = {0.f, 0.f, 0.f, 0.f};
#pragma unroll
    for (int kb = 0; kb < 8; ++kb) {
        const int k4 = kb * 16 + q * 4;
        float4 wf = *(const float4*)(Wrow + k4);
        s4 a  = pack4(wf.x, wf.y, wf.z, wf.w);
        s4 bb = *(const s4*)(Hrow + k4);    // B[k][n=j] = Ht[b][j][k]
        acc = MFMA16(a, bb, acc);
    }

    float* op = out + ((size_t)b * D_ + o0 + q * 4) * L_ + j16 + m;
    op[0]      = acc[0]; op[L_]     = acc[1];
    op[2 * L_] = acc[2]; op[3 * L_] = acc[3];
}

// ---------------------------------------------------------------------------
extern "C" void kernel_launch(void* const* d_in, const int* in_sizes, int n_in,
                              void* d_out, int out_size, void* d_ws, size_t ws_size,
                              hipStream_t stream) {
    const float* x  = (const float*)d_in[0];
    const float* Wq = (const float*)d_in[1];
    const float* Wk = (const float*)d_in[2];
    const float* Wv = (const float*)d_in[3];
    const float* Wo = (const float*)d_in[4];
    float* out = (float*)d_out;

    const size_t SEG = (size_t)B_ * NH * DK * L_;   // 1,048,576 elements
    unsigned short* Qt = (unsigned short*)d_ws;     // bf16 [bh][l][k], 2 MB
    unsigned short* Kt = Qt + SEG;                  // bf16 [bh][j][k], 2 MB
    unsigned short* Vt = Kt + SEG;                  // bf16 [bh][v][i], 2 MB
    unsigned short* Ht = Vt + SEG;                  // bf16 [b][j][d],  2 MB

    proj_kernel<<<dim3(16, B_ * NH), 256, 0, stream>>>(x, Wq, Wk, Wv, Qt, Kt, Vt);
    attn_kernel<<<dim3(4, B_ * NH), 1024, 0, stream>>>(Qt, Kt, Vt, Ht);
    outproj_kernel<<<dim3(32, B_), 1024, 0, stream>>>(Ht, Wo, out);
}